// Round 6
// baseline (530.629 us; speedup 1.0000x reference)
//
#include <hip/hip_runtime.h>
#include <hip/hip_fp16.h>
#include <math.h>

#define W_ 512
#define H_ 512
#define D_ 64
#define PLANE ((size_t)(W_ * H_))
#define TXX 128
#define TYY 16
#define TS 16
#define ROWU 321    // uints per xblur LDS row: 128 (f01) + 128 (f23) + 64 (f4 half2) + 1 pad
#define RAWS 148    // floats per raw LDS row (144 used + 4 pad; 16B-aligned stride)

typedef unsigned int uint;
typedef float f32x2 __attribute__((ext_vector_type(2)));

// w[11]: scalar taps. wp2[2*i]=WT(i), wp2[2*i+1]=WT(i-1) for i=0..11 (WT zero-padded):
// packed weight pair for an (even,odd) output pair at even-output tap te=i -> v_pk_fma_f32.
struct GWS { float w[11]; float wp2[24]; };

__device__ __forceinline__ uint pack2h(float a, float b) {
    __half2 h = __floats2half2_rn(a, b);
    return *(uint*)&h;
}
__device__ __forceinline__ float2 unpack2h(uint u) {
    return __half22float2(*(__half2*)&u);
}
// async global->LDS DMA, 16 B per active lane; lds dest = base + lane*16
__device__ __forceinline__ void dma16(const float* g, float* l) {
    __builtin_amdgcn_global_load_lds(
        (const __attribute__((address_space(1))) uint*)g,
        (__attribute__((address_space(3))) uint*)l, 16, 0, 0);
}

// ---------------- K1: per-slice 2D blur (x then y) of 5 fields -> one packed 12B/voxel plane --
// LDS union: raw staging and bufA share one 33.4 KB allocation (retire barrier between).
// 4 blocks/CU (LDS-capped); __launch_bounds__(256,2) avoids the (256,4) spill-to-64-VGPR.
// FIR inner loops use v_pk_fma_f32 (2 outputs/instr via __builtin_elementwise_fma on f32x2):
// phase-1 880->480 VALU, phase-2 440->240. Zero-padded edge weights keep results bit-identical
// (fma(0,v,acc)==acc; per-output tap order unchanged).
__global__ __launch_bounds__(256, 2) void k1_blur2d(
    const float* __restrict__ X, const float* __restrict__ Y,
    uint3* __restrict__ B, int zA, int S, GWS gw)
{
    __shared__ __align__(16) uint ldsu[26 * ROWU];    // 33.4 KB union
    float* rawX = (float*)ldsu;                       // 26 rows x RAWS floats
    float* rawY = rawX + 26 * RAWS;                   // 26 rows x RAWS floats (ends at 30.8 KB)
    uint*  bufA = ldsu;                               // overwrites raw after the retire barrier
    const int zi  = zA + blockIdx.z;
    const int ty0 = blockIdx.y * TYY;
    const int tx0 = blockIdx.x * TXX;
    const float* __restrict__ px = X + (size_t)zi * PLANE;
    const float* __restrict__ py = Y + (size_t)zi * PLANE;
    const int tid  = threadIdx.x;
    const int wave = tid >> 6, lane = tid & 63;
    const int w0 = min(max(tx0 - 8, 0), W_ - 144);    // staged window start (144 floats/row)
    const f32x2 z2 = {0.f, 0.f};

    // ---- DMA stage: 52 row-copies (26 rows x 2 fields), 13 per wave, 36 lanes x 16 B each ----
    #pragma unroll
    for (int i = 0; i < 13; ++i) {
        const int cid = wave * 13 + i;                // 0..51, wave-uniform
        const int rr2 = cid >> 1, f = cid & 1;
        const int yy = min(max(ty0 + rr2 - 5, 0), H_ - 1);
        const float* srcrow = (f ? py : px) + (size_t)yy * W_ + w0;
        float* dstrow = (f ? rawY : rawX) + rr2 * RAWS;
        if (lane < 36) dma16(srcrow + lane * 4, dstrow);
    }
    __syncthreads();   // drains vmcnt(0): DMA complete

    // ---- Phase 1: x-blur at 26 halo rows from LDS raw; task = (row r, 16-wide segment s) ----
    const int r = tid & 31;        // 0..31, use 0..25  (map: boundary divergence in 2 half-waves)
    const int s = tid >> 5;        // 0..7
    f32x2 A0[8], A1[8], A2[8], A3[8], A4[8];          // 8 output-pairs per field
    if (r < 26) {
        const int xb = tx0 + s * TS - 5;
        const bool interior = (xb >= 3) && (xb + 29 <= W_);
        const float* rx = rawX + r * RAWS;
        const float* ry = rawY + r * RAWS;
        float4 qx[8], qy[8];
        if (interior) {
            const int b = s * 16 + (tx0 - 8 - w0);   // dword idx, multiple of 4
            #pragma unroll
            for (int k = 0; k < 8; ++k) {
                qx[k] = *(const float4*)(rx + b + 4 * k);
                qy[k] = *(const float4*)(ry + b + 4 * k);
            }
        } else {
            #pragma unroll
            for (int k = 0; k < 8; ++k)
                #pragma unroll
                for (int m = 0; m < 4; ++m) {
                    const int g = min(max(xb + (4 * k + m - 3), 0), W_ - 1) - w0;
                    ((float*)&qx[k])[m] = rx[g];
                    ((float*)&qy[k])[m] = ry[g];
                }
        }

        #pragma unroll
        for (int op = 0; op < 8; ++op) { A0[op]=z2; A1[op]=z2; A2[op]=z2; A3[op]=z2; A4[op]=z2; }

        #pragma unroll
        for (int k = 0; k < 8; ++k) {
            #pragma unroll
            for (int m = 0; m < 4; ++m) {
                const int c = 4 * k + m - 3;       // compile-time
                if (c < 0 || c > 25) continue;
                const float vx = ((float*)&qx[k])[m];
                const float vy = ((float*)&qy[k])[m];
                const float pxx = vx * vx, pyy = vy * vy, pxy = vx * vy;
                const f32x2 Vx = {vx, vx}, Vy = {vy, vy};
                const f32x2 Px = {pxx, pxx}, Py = {pyy, pyy}, Pz = {pxy, pxy};
                #pragma unroll
                for (int op = 0; op < 8; ++op) {
                    const int te = c - 2 * op;     // compile-time; even output's tap
                    if (te < 0 || te > 11) continue;
                    f32x2 wv; wv.x = gw.wp2[2 * te]; wv.y = gw.wp2[2 * te + 1];
                    A0[op] = __builtin_elementwise_fma(wv, Vx, A0[op]);
                    A1[op] = __builtin_elementwise_fma(wv, Vy, A1[op]);
                    A2[op] = __builtin_elementwise_fma(wv, Px, A2[op]);
                    A3[op] = __builtin_elementwise_fma(wv, Py, A3[op]);
                    A4[op] = __builtin_elementwise_fma(wv, Pz, A4[op]);
                }
            }
        }
    }
    __syncthreads();   // retire all raw-LDS reads (results live in A0..A4) before overwrite

    if (r < 26) {
        uint* row0 = bufA + r * ROWU;
        #pragma unroll
        for (int o2 = 0; o2 < TS / 2; ++o2) {
            const int col = s * TS + 2 * o2;
            uint2 u01 = make_uint2(pack2h(A0[o2].x, A1[o2].x), pack2h(A0[o2].y, A1[o2].y));
            uint2 u23 = make_uint2(pack2h(A2[o2].x, A3[o2].x), pack2h(A2[o2].y, A3[o2].y));
            *(uint2*)(row0 + col)        = u01;
            *(uint2*)(row0 + 128 + col)  = u23;
            row0[256 + s * 8 + o2]       = pack2h(A4[o2].x, A4[o2].y);
        }
    }
    __syncthreads();

    // ---- Phase 2: y-blur; task = (column x, 8-high segment); one uint3 store per voxel ----
    {
        const int x   = tid & (TXX - 1);
        const int seg = tid >> 7;      // 0..1
        f32x2 AC[5][4];                // 4 output-pairs per field
        #pragma unroll
        for (int f = 0; f < 5; ++f)
            #pragma unroll
            for (int op = 0; op < 4; ++op) AC[f][op] = z2;
        #pragma unroll
        for (int rr = 0; rr < 18; ++rr) {
            const uint* row0 = bufA + (seg * 8 + rr) * ROWU;
            const float2 f01 = unpack2h(row0[x]);
            const float2 f23 = unpack2h(row0[128 + x]);
            const float  b4  = __half2float(((const __half*)(row0 + 256))[x]);
            const f32x2 B0 = {f01.x, f01.x}, B1 = {f01.y, f01.y};
            const f32x2 B2 = {f23.x, f23.x}, B3 = {f23.y, f23.y};
            const f32x2 B4 = {b4, b4};
            #pragma unroll
            for (int op = 0; op < 4; ++op) {
                const int te = rr - 2 * op;        // compile-time
                if (te < 0 || te > 11) continue;
                f32x2 wv; wv.x = gw.wp2[2 * te]; wv.y = gw.wp2[2 * te + 1];
                AC[0][op] = __builtin_elementwise_fma(wv, B0, AC[0][op]);
                AC[1][op] = __builtin_elementwise_fma(wv, B1, AC[1][op]);
                AC[2][op] = __builtin_elementwise_fma(wv, B2, AC[2][op]);
                AC[3][op] = __builtin_elementwise_fma(wv, B3, AC[3][op]);
                AC[4][op] = __builtin_elementwise_fma(wv, B4, AC[4][op]);
            }
        }
        const int slot = blockIdx.z;
        #pragma unroll
        for (int o = 0; o < 8; ++o) {              // o compile-time -> static .x/.y select
            const int op = o >> 1;
            const float c0 = (o & 1) ? AC[0][op].y : AC[0][op].x;
            const float c1 = (o & 1) ? AC[1][op].y : AC[1][op].x;
            const float c2 = (o & 1) ? AC[2][op].y : AC[2][op].x;
            const float c3 = (o & 1) ? AC[3][op].y : AC[3][op].x;
            const float c4 = (o & 1) ? AC[4][op].y : AC[4][op].x;
            const size_t pix = (size_t)(ty0 + seg * 8 + o) * W_ + tx0 + x;
            B[(size_t)slot * PLANE + pix] =
                make_uint3(pack2h(c0, c1), pack2h(c2, c3), pack2h(c4, 0.f));
        }
    }
}

// ---------------- K2: z-blur (register ring FIR, depth-11 prefetch) + SSIM + reduction ------
// Ring FIR packs fields (0,1) and (2,3) into f32x2 with broadcast weight: 55->33 FMA/step.
__global__ __launch_bounds__(256, 3) void k2_blurz_ssim(
    const uint3* __restrict__ B, float* __restrict__ slots,
    int z0, int CZ2, int zA, int S, GWS gw)
{
    const int x = blockIdx.x * 256 + threadIdx.x;
    const int y = blockIdx.y;
    const int zz0 = z0 + blockIdx.z * CZ2;       // first output z of this sub-chunk
    const size_t pix = (size_t)y * W_ + x;
    const uint3* __restrict__ Bp = B + pix;
    const f32x2 z2 = {0.f, 0.f};

    f32x2 R01[11], R23[11];
    float r4[11];
    #pragma unroll
    for (int i = 0; i < 11; ++i) { R01[i] = z2; R23[i] = z2; r4[i] = 0.f; }
    float lsum = 0.f;

    // prefetch ring: pf[u] holds step jb+u's data; reloaded for +11 right after consumption
    uint3 pf[11];
    #pragma unroll
    for (int u = 0; u < 11; ++u) {
        const int slot = min(max(zz0 - 5 + u - zA, 0), S - 1);
        pf[u] = Bp[(size_t)slot * PLANE];
    }

    const int JT = ((CZ2 + 20) / 11) * 11;       // >= CZ2+10, multiple of 11
    for (int jb = 0; jb < JT; jb += 11) {
        #pragma unroll
        for (int u = 0; u < 11; ++u) {
            const int j = jb + u;
            const uint3 v = pf[u];
            {   // issue prefetch for j+11 immediately (consumed 11 steps later)
                const int slot = min(max(zz0 - 5 + j + 11 - zA, 0), S - 1);
                pf[u] = Bp[(size_t)slot * PLANE];
            }
            const float2 f01 = unpack2h(v.x);
            const float2 f23 = unpack2h(v.y);
            const float v4 = __half2float(*(const __half*)&v.z);
            const f32x2 V01 = {f01.x, f01.y}, V23 = {f23.x, f23.y};

            // Unconditional taps: an out-of-range output's slot is never emitted and
            // is zeroed on recycle, so stray contributions are harmless.
            #pragma unroll
            for (int t = 0; t <= 10; ++t) {
                const int sl = (u + 11 - t) % 11;   // compile-time
                const float wt = gw.w[t];
                const f32x2 Wb = {wt, wt};
                R01[sl] = __builtin_elementwise_fma(Wb, V01, R01[sl]);
                R23[sl] = __builtin_elementwise_fma(Wb, V23, R23[sl]);
                r4[sl]  = fmaf(wt, v4, r4[sl]);
            }
            const int sl0 = (u + 1) % 11;        // slot completed this step
            if (j >= 10 && (j - 10) < CZ2) {     // wave-uniform emit guard
                const float mx = R01[sl0].x, my = R01[sl0].y;
                const float exx = R23[sl0].x, eyy = R23[sl0].y, exy = r4[sl0];
                const float mx2 = mx * mx, my2 = my * my, mxy = mx * my;
                const float sx  = fmaxf(exx - mx2, 0.f);
                const float sy  = fmaxf(eyy - my2, 0.f);
                const float sxy = exy - mxy;
                const float num = (2.f * mxy + 1e-4f) * (2.f * sxy + 9e-4f);
                const float den = (mx2 + my2 + 1e-4f) * (sx + sy + 9e-4f);
                lsum += num * __builtin_amdgcn_rcpf(den);
            }
            R01[sl0] = z2; R23[sl0] = z2; r4[sl0] = 0.f;
        }
    }

    // block reduction: wave shuffle -> LDS -> one atomic per block into 64 padded slots
    #pragma unroll
    for (int off = 32; off > 0; off >>= 1) lsum += __shfl_down(lsum, off);
    __shared__ float part[4];
    if ((threadIdx.x & 63) == 0) part[threadIdx.x >> 6] = lsum;
    __syncthreads();
    if (threadIdx.x == 0) {
        const float v = part[0] + part[1] + part[2] + part[3];
        const int si = (blockIdx.y + blockIdx.x * 17 + blockIdx.z * 29) & 63;
        atomicAdd(slots + si * 16, v);           // 64 B stride per slot
    }
}

__global__ void k3_final(const float* __restrict__ slots, float* __restrict__ out)
{
    float v = slots[threadIdx.x * 16];           // 64 threads
    #pragma unroll
    for (int off = 32; off > 0; off >>= 1) v += __shfl_down(v, off);
    if (threadIdx.x == 0) out[0] = v * (1.f / 33554432.f);   // / 2^25 voxels
}

extern "C" void kernel_launch(void* const* d_in, const int* in_sizes, int n_in,
                              void* d_out, int out_size, void* d_ws, size_t ws_size,
                              hipStream_t stream)
{
    const float* X = (const float*)d_in[0];
    const float* Y = (const float*)d_in[1];
    float* out   = (float*)d_out;
    float* slots = (float*)d_ws;                 // 64 slots x 64 B = 4 KB
    uint3* buf   = (uint3*)((char*)d_ws + 4096);
    const size_t avail = (ws_size > 4096) ? ws_size - 4096 : 0;

    // pick largest z-chunk whose packed intermediate (12 B/voxel) fits the workspace
    const int czs[7] = {64, 32, 16, 8, 4, 2, 1};
    int CZ = 1;
    for (int i = 0; i < 7; ++i) {
        int smax = czs[i] + 10; if (smax > D_) smax = D_;
        size_t need = (size_t)smax * PLANE * 12;
        if (need <= avail) { CZ = czs[i]; break; }
    }

    GWS gw;
    {
        double g[11], s = 0.0;
        for (int i = 0; i < 11; ++i) { double c = i - 5; g[i] = exp(-(c * c) / 4.5); s += g[i]; }
        for (int i = 0; i < 11; ++i) gw.w[i] = (float)(g[i] / s);
        for (int i = 0; i < 12; ++i) {           // packed pair table: (WT(i), WT(i-1)), 0-padded
            gw.wp2[2 * i]     = (i <= 10) ? gw.w[i] : 0.f;
            gw.wp2[2 * i + 1] = (i >= 1 && i - 1 <= 10) ? gw.w[i - 1] : 0.f;
        }
    }

    hipMemsetAsync(d_ws, 0, 4096, stream);       // zero the accumulator slots

    for (int n = 0; n < 2; ++n) {
        const float* Xn = X + (size_t)n * D_ * PLANE;
        const float* Yn = Y + (size_t)n * D_ * PLANE;
        for (int z0 = 0; z0 < D_; z0 += CZ) {
            const int zAv = (z0 - 5 > 0) ? z0 - 5 : 0;
            int zBv = z0 + CZ + 5; if (zBv > D_) zBv = D_;
            const int S = zBv - zAv;
            const int CZ2 = (CZ >= 2) ? CZ / 2 : CZ;
            const int SC  = (CZ >= 2) ? 2 : 1;
            k1_blur2d<<<dim3(W_ / TXX, H_ / TYY, S), 256, 0, stream>>>(Xn, Yn, buf, zAv, S, gw);
            k2_blurz_ssim<<<dim3(W_ / 256, H_, SC), 256, 0, stream>>>(buf, slots, z0, CZ2, zAv, S, gw);
        }
    }
    k3_final<<<1, 64, 0, stream>>>(slots, out);
}

// Round 7
// 494.083 us; speedup vs baseline: 1.0740x; 1.0740x over previous
//
#include <hip/hip_runtime.h>
#include <hip/hip_fp16.h>
#include <math.h>

#define W_ 512
#define H_ 512
#define D_ 64
#define PLANE ((size_t)(W_ * H_))
#define TXX 128
#define TYY 16
#define TS 16
#define ROWU 321    // uints per xblur LDS row: 128 (f01) + 128 (f23) + 64 (f4 half2) + 1 pad
#define RAWS 148    // floats per raw LDS row (144 used + 4 pad; 16B-aligned stride)

typedef unsigned int uint;
typedef float f32x2 __attribute__((ext_vector_type(2)));

struct GWS { float w[11]; };

__device__ __forceinline__ uint pack2h(float a, float b) {
    __half2 h = __floats2half2_rn(a, b);
    return *(uint*)&h;
}
__device__ __forceinline__ float2 unpack2h(uint u) {
    return __half22float2(*(__half2*)&u);
}
// async global->LDS DMA, 16 B per active lane; lds dest = base + lane*16
__device__ __forceinline__ void dma16(const float* g, float* l) {
    __builtin_amdgcn_global_load_lds(
        (const __attribute__((address_space(1))) uint*)g,
        (__attribute__((address_space(3))) uint*)l, 16, 0, 0);
}

// ---------------- K1: per-slice 2D blur (x then y) of 5 fields -> one packed 12B/voxel plane --
// LDS union: raw staging and bufA share one 33.4 KB allocation (retire barrier between).
// 4 blocks/CU (LDS-capped); __launch_bounds__(256,2) avoids the (256,4) spill-to-64-VGPR.
// SCALAR fmaf inner loops (Round-5 form): the pk_fma variant REGRESSED here (150 vs 119 us) —
// broadcast/pair materialization ate the issue savings and halved accumulator ILP (VALUBusy
// 65->48). Task map r=tid&31,s=tid>>5 keeps boundary divergence in 2 half-waves.
__global__ __launch_bounds__(256, 2) void k1_blur2d(
    const float* __restrict__ X, const float* __restrict__ Y,
    uint3* __restrict__ B, int zA, int S, GWS gw)
{
    __shared__ __align__(16) uint ldsu[26 * ROWU];    // 33.4 KB union
    float* rawX = (float*)ldsu;                       // 26 rows x RAWS floats
    float* rawY = rawX + 26 * RAWS;                   // 26 rows x RAWS floats (ends at 30.8 KB)
    uint*  bufA = ldsu;                               // overwrites raw after the retire barrier
    const int zi  = zA + blockIdx.z;
    const int ty0 = blockIdx.y * TYY;
    const int tx0 = blockIdx.x * TXX;
    const float* __restrict__ px = X + (size_t)zi * PLANE;
    const float* __restrict__ py = Y + (size_t)zi * PLANE;
    const int tid  = threadIdx.x;
    const int wave = tid >> 6, lane = tid & 63;
    const int w0 = min(max(tx0 - 8, 0), W_ - 144);    // staged window start (144 floats/row)

    // ---- DMA stage: 52 row-copies (26 rows x 2 fields), 13 per wave, 36 lanes x 16 B each ----
    #pragma unroll
    for (int i = 0; i < 13; ++i) {
        const int cid = wave * 13 + i;                // 0..51, wave-uniform
        const int rr2 = cid >> 1, f = cid & 1;
        const int yy = min(max(ty0 + rr2 - 5, 0), H_ - 1);
        const float* srcrow = (f ? py : px) + (size_t)yy * W_ + w0;
        float* dstrow = (f ? rawY : rawX) + rr2 * RAWS;
        if (lane < 36) dma16(srcrow + lane * 4, dstrow);
    }
    __syncthreads();   // drains vmcnt(0): DMA complete

    // ---- Phase 1: x-blur at 26 halo rows from LDS raw; task = (row r, 16-wide segment s) ----
    const int r = tid & 31;        // 0..31, use 0..25  (bank/divergence-friendly map)
    const int s = tid >> 5;        // 0..7
    float a0[TS], a1[TS], a2[TS], a3[TS], a4[TS];
    if (r < 26) {
        const int xb = tx0 + s * TS - 5;
        const bool interior = (xb >= 3) && (xb + 29 <= W_);
        const float* rx = rawX + r * RAWS;
        const float* ry = rawY + r * RAWS;
        float4 qx[8], qy[8];
        if (interior) {
            const int b = s * 16 + (tx0 - 8 - w0);   // dword idx, multiple of 4
            #pragma unroll
            for (int k = 0; k < 8; ++k) {
                qx[k] = *(const float4*)(rx + b + 4 * k);
                qy[k] = *(const float4*)(ry + b + 4 * k);
            }
        } else {
            #pragma unroll
            for (int k = 0; k < 8; ++k)
                #pragma unroll
                for (int m = 0; m < 4; ++m) {
                    const int g = min(max(xb + (4 * k + m - 3), 0), W_ - 1) - w0;
                    ((float*)&qx[k])[m] = rx[g];
                    ((float*)&qy[k])[m] = ry[g];
                }
        }

        #pragma unroll
        for (int o = 0; o < TS; ++o) { a0[o]=0.f; a1[o]=0.f; a2[o]=0.f; a3[o]=0.f; a4[o]=0.f; }

        #pragma unroll
        for (int k = 0; k < 8; ++k) {
            #pragma unroll
            for (int m = 0; m < 4; ++m) {
                const int c = 4 * k + m - 3;       // compile-time
                if (c < 0 || c > 25) continue;
                const float vx = ((float*)&qx[k])[m];
                const float vy = ((float*)&qy[k])[m];
                const float pxx = vx * vx, pyy = vy * vy, pxy = vx * vy;
                #pragma unroll
                for (int o = 0; o < TS; ++o) {
                    const int t = c - o;
                    if (t >= 0 && t <= 10) {
                        const float w = gw.w[t];
                        a0[o] = fmaf(w, vx,  a0[o]);
                        a1[o] = fmaf(w, vy,  a1[o]);
                        a2[o] = fmaf(w, pxx, a2[o]);
                        a3[o] = fmaf(w, pyy, a3[o]);
                        a4[o] = fmaf(w, pxy, a4[o]);
                    }
                }
            }
        }
    }
    __syncthreads();   // retire all raw-LDS reads (results live in a0..a4) before overwrite

    if (r < 26) {
        uint* row0 = bufA + r * ROWU;
        #pragma unroll
        for (int o2 = 0; o2 < TS / 2; ++o2) {
            const int col = s * TS + 2 * o2;
            uint2 u01 = make_uint2(pack2h(a0[2*o2], a1[2*o2]), pack2h(a0[2*o2+1], a1[2*o2+1]));
            uint2 u23 = make_uint2(pack2h(a2[2*o2], a3[2*o2]), pack2h(a2[2*o2+1], a3[2*o2+1]));
            *(uint2*)(row0 + col)        = u01;
            *(uint2*)(row0 + 128 + col)  = u23;
            row0[256 + s * 8 + o2]       = pack2h(a4[2*o2], a4[2*o2+1]);
        }
    }
    __syncthreads();

    // ---- Phase 2: y-blur; task = (column x, 8-high segment); one uint3 store per voxel ----
    {
        const int x   = tid & (TXX - 1);
        const int seg = tid >> 7;      // 0..1
        float acc[5][8];
        #pragma unroll
        for (int f = 0; f < 5; ++f)
            #pragma unroll
            for (int o = 0; o < 8; ++o) acc[f][o] = 0.f;
        #pragma unroll
        for (int rr = 0; rr < 18; ++rr) {
            const uint* row0 = bufA + (seg * 8 + rr) * ROWU;
            const float2 f01 = unpack2h(row0[x]);
            const float2 f23 = unpack2h(row0[128 + x]);
            const float  b4  = __half2float(((const __half*)(row0 + 256))[x]);
            const float b0 = f01.x, b1 = f01.y, b2 = f23.x, b3 = f23.y;
            #pragma unroll
            for (int o = 0; o < 8; ++o) {
                const int t = rr - o;
                if (t >= 0 && t <= 10) {
                    const float w = gw.w[t];
                    acc[0][o] = fmaf(w, b0, acc[0][o]);
                    acc[1][o] = fmaf(w, b1, acc[1][o]);
                    acc[2][o] = fmaf(w, b2, acc[2][o]);
                    acc[3][o] = fmaf(w, b3, acc[3][o]);
                    acc[4][o] = fmaf(w, b4, acc[4][o]);
                }
            }
        }
        const int slot = blockIdx.z;
        #pragma unroll
        for (int o = 0; o < 8; ++o) {
            const size_t pix = (size_t)(ty0 + seg * 8 + o) * W_ + tx0 + x;
            B[(size_t)slot * PLANE + pix] =
                make_uint3(pack2h(acc[0][o], acc[1][o]),
                           pack2h(acc[2][o], acc[3][o]),
                           pack2h(acc[4][o], 0.f));
        }
    }
}

// ---------------- K2: z-blur (register ring FIR, depth-11 prefetch) + SSIM + reduction ------
// Ring FIR packs fields (0,1) and (2,3) into f32x2 with broadcast weight: 55->33 FMA/step.
// This pk variant WON in k2 (~130 -> ~113 us, Round-6 accounting): fields are already paired
// in registers and the weight is a broadcast, so no extra data movement — unlike k1's variant.
__global__ __launch_bounds__(256, 3) void k2_blurz_ssim(
    const uint3* __restrict__ B, float* __restrict__ slots,
    int z0, int CZ2, int zA, int S, GWS gw)
{
    const int x = blockIdx.x * 256 + threadIdx.x;
    const int y = blockIdx.y;
    const int zz0 = z0 + blockIdx.z * CZ2;       // first output z of this sub-chunk
    const size_t pix = (size_t)y * W_ + x;
    const uint3* __restrict__ Bp = B + pix;
    const f32x2 z2 = {0.f, 0.f};

    f32x2 R01[11], R23[11];
    float r4[11];
    #pragma unroll
    for (int i = 0; i < 11; ++i) { R01[i] = z2; R23[i] = z2; r4[i] = 0.f; }
    float lsum = 0.f;

    // prefetch ring: pf[u] holds step jb+u's data; reloaded for +11 right after consumption
    uint3 pf[11];
    #pragma unroll
    for (int u = 0; u < 11; ++u) {
        const int slot = min(max(zz0 - 5 + u - zA, 0), S - 1);
        pf[u] = Bp[(size_t)slot * PLANE];
    }

    const int JT = ((CZ2 + 20) / 11) * 11;       // >= CZ2+10, multiple of 11
    for (int jb = 0; jb < JT; jb += 11) {
        #pragma unroll
        for (int u = 0; u < 11; ++u) {
            const int j = jb + u;
            const uint3 v = pf[u];
            {   // issue prefetch for j+11 immediately (consumed 11 steps later)
                const int slot = min(max(zz0 - 5 + j + 11 - zA, 0), S - 1);
                pf[u] = Bp[(size_t)slot * PLANE];
            }
            const float2 f01 = unpack2h(v.x);
            const float2 f23 = unpack2h(v.y);
            const float v4 = __half2float(*(const __half*)&v.z);
            const f32x2 V01 = {f01.x, f01.y}, V23 = {f23.x, f23.y};

            // Unconditional taps: an out-of-range output's slot is never emitted and
            // is zeroed on recycle, so stray contributions are harmless.
            #pragma unroll
            for (int t = 0; t <= 10; ++t) {
                const int sl = (u + 11 - t) % 11;   // compile-time
                const float wt = gw.w[t];
                const f32x2 Wb = {wt, wt};
                R01[sl] = __builtin_elementwise_fma(Wb, V01, R01[sl]);
                R23[sl] = __builtin_elementwise_fma(Wb, V23, R23[sl]);
                r4[sl]  = fmaf(wt, v4, r4[sl]);
            }
            const int sl0 = (u + 1) % 11;        // slot completed this step
            if (j >= 10 && (j - 10) < CZ2) {     // wave-uniform emit guard
                const float mx = R01[sl0].x, my = R01[sl0].y;
                const float exx = R23[sl0].x, eyy = R23[sl0].y, exy = r4[sl0];
                const float mx2 = mx * mx, my2 = my * my, mxy = mx * my;
                const float sx  = fmaxf(exx - mx2, 0.f);
                const float sy  = fmaxf(eyy - my2, 0.f);
                const float sxy = exy - mxy;
                const float num = (2.f * mxy + 1e-4f) * (2.f * sxy + 9e-4f);
                const float den = (mx2 + my2 + 1e-4f) * (sx + sy + 9e-4f);
                lsum += num * __builtin_amdgcn_rcpf(den);
            }
            R01[sl0] = z2; R23[sl0] = z2; r4[sl0] = 0.f;
        }
    }

    // block reduction: wave shuffle -> LDS -> one atomic per block into 64 padded slots
    #pragma unroll
    for (int off = 32; off > 0; off >>= 1) lsum += __shfl_down(lsum, off);
    __shared__ float part[4];
    if ((threadIdx.x & 63) == 0) part[threadIdx.x >> 6] = lsum;
    __syncthreads();
    if (threadIdx.x == 0) {
        const float v = part[0] + part[1] + part[2] + part[3];
        const int si = (blockIdx.y + blockIdx.x * 17 + blockIdx.z * 29) & 63;
        atomicAdd(slots + si * 16, v);           // 64 B stride per slot
    }
}

__global__ void k3_final(const float* __restrict__ slots, float* __restrict__ out)
{
    float v = slots[threadIdx.x * 16];           // 64 threads
    #pragma unroll
    for (int off = 32; off > 0; off >>= 1) v += __shfl_down(v, off);
    if (threadIdx.x == 0) out[0] = v * (1.f / 33554432.f);   // / 2^25 voxels
}

extern "C" void kernel_launch(void* const* d_in, const int* in_sizes, int n_in,
                              void* d_out, int out_size, void* d_ws, size_t ws_size,
                              hipStream_t stream)
{
    const float* X = (const float*)d_in[0];
    const float* Y = (const float*)d_in[1];
    float* out   = (float*)d_out;
    float* slots = (float*)d_ws;                 // 64 slots x 64 B = 4 KB
    uint3* buf   = (uint3*)((char*)d_ws + 4096);
    const size_t avail = (ws_size > 4096) ? ws_size - 4096 : 0;

    // pick largest z-chunk whose packed intermediate (12 B/voxel) fits the workspace
    const int czs[7] = {64, 32, 16, 8, 4, 2, 1};
    int CZ = 1;
    for (int i = 0; i < 7; ++i) {
        int smax = czs[i] + 10; if (smax > D_) smax = D_;
        size_t need = (size_t)smax * PLANE * 12;
        if (need <= avail) { CZ = czs[i]; break; }
    }

    GWS gw;
    {
        double g[11], s = 0.0;
        for (int i = 0; i < 11; ++i) { double c = i - 5; g[i] = exp(-(c * c) / 4.5); s += g[i]; }
        for (int i = 0; i < 11; ++i) gw.w[i] = (float)(g[i] / s);
    }

    hipMemsetAsync(d_ws, 0, 4096, stream);       // zero the accumulator slots

    for (int n = 0; n < 2; ++n) {
        const float* Xn = X + (size_t)n * D_ * PLANE;
        const float* Yn = Y + (size_t)n * D_ * PLANE;
        for (int z0 = 0; z0 < D_; z0 += CZ) {
            const int zAv = (z0 - 5 > 0) ? z0 - 5 : 0;
            int zBv = z0 + CZ + 5; if (zBv > D_) zBv = D_;
            const int S = zBv - zAv;
            const int CZ2 = (CZ >= 2) ? CZ / 2 : CZ;
            const int SC  = (CZ >= 2) ? 2 : 1;
            k1_blur2d<<<dim3(W_ / TXX, H_ / TYY, S), 256, 0, stream>>>(Xn, Yn, buf, zAv, S, gw);
            k2_blurz_ssim<<<dim3(W_ / 256, H_, SC), 256, 0, stream>>>(buf, slots, z0, CZ2, zAv, S, gw);
        }
    }
    k3_final<<<1, 64, 0, stream>>>(slots, out);
}